// Round 1
// baseline (517.305 us; speedup 1.0000x reference)
//
#include <hip/hip_runtime.h>
#include <cstdint>

typedef __bf16 bf16;
typedef bf16 bf16x8 __attribute__((ext_vector_type(8)));
typedef bf16 bf16x4 __attribute__((ext_vector_type(4)));
typedef float f32x4 __attribute__((ext_vector_type(4)));

#define MFMA16(a, b, c) __builtin_amdgcn_mfma_f32_16x16x32_bf16((a), (b), (c), 0, 0, 0)

#define GLOBAL_TO_LDS16(gptr, lptr)                                          \
  __builtin_amdgcn_global_load_lds(                                          \
      (const __attribute__((address_space(1))) void*)(gptr),                 \
      (__attribute__((address_space(3))) void*)(lptr), 16, 0, 0)

// problem dims: H=16, D=1024, DK=DV=64, B=4, SQ=SK=1024, scale = 32

// ---------------------------------------------------------------------------
// 1) flat fp32 -> bf16 convert for query/key/value/w_proj
// ---------------------------------------------------------------------------
__global__ __launch_bounds__(256) void cvt_all(
    const float* __restrict__ q, const float* __restrict__ k,
    const float* __restrict__ v, const float* __restrict__ wp,
    bf16* __restrict__ qb, bf16* __restrict__ kb,
    bf16* __restrict__ vb, bf16* __restrict__ wpb) {
  long i4 = ((long)blockIdx.x * 256 + threadIdx.x) * 4;
  const float* src;
  bf16* dst;
  long off;
  if (i4 < 4194304) {
    src = q; dst = qb; off = i4;
  } else if (i4 < 8388608) {
    src = k; dst = kb; off = i4 - 4194304;
  } else if (i4 < 12582912) {
    src = v; dst = vb; off = i4 - 8388608;
  } else {
    src = wp; dst = wpb; off = i4 - 12582912;
  }
  float4 f = *(const float4*)(src + off);
  bf16x4 o;
  o[0] = (bf16)f.x; o[1] = (bf16)f.y; o[2] = (bf16)f.z; o[3] = (bf16)f.w;
  *(bf16x4*)(dst + off) = o;
}

// ---------------------------------------------------------------------------
// 2) LDS-tiled transpose: w_{q,k,v}[h][d][kk] fp32 -> wT[h*64+kk][d] bf16
//    grid (16 d-tiles, 16 h, 3 matrices), block 256
// ---------------------------------------------------------------------------
__global__ __launch_bounds__(256) void wtrans(
    const float* __restrict__ wq, const float* __restrict__ wk,
    const float* __restrict__ wv, bf16* __restrict__ wqT,
    bf16* __restrict__ wkT, bf16* __restrict__ wvT) {
  __shared__ bf16 tile[64][72];  // 72: 144 B row stride, conflict-free gather
  int dt = blockIdx.x, h = blockIdx.y, z = blockIdx.z;
  const float* src =
      ((z == 0) ? wq : (z == 1) ? wk : wv) + (long)h * 65536 + dt * 64 * 64;
  bf16* dstM = (z == 0) ? wqT : (z == 1) ? wkT : wvT;
  int t = threadIdx.x;
#pragma unroll
  for (int i = 0; i < 4; ++i) {
    int chunk = t + i * 256;           // 1024 chunks of 4 floats
    int r = chunk >> 4, c4 = chunk & 15;
    float4 f = *(const float4*)(src + r * 64 + c4 * 4);
    bf16x4 o;
    o[0] = (bf16)f.x; o[1] = (bf16)f.y; o[2] = (bf16)f.z; o[3] = (bf16)f.w;
    *(bf16x4*)&tile[r][c4 * 4] = o;
  }
  __syncthreads();
  int kk = t & 63, sc = t >> 6;        // gather 16 d's for this kk
  bf16 tmp[16];
#pragma unroll
  for (int j = 0; j < 16; ++j) tmp[j] = tile[sc * 16 + j][kk];
  bf16* dst = dstM + ((long)h * 64 + kk) * 1024 + dt * 64 + sc * 16;
  *(bf16x8*)dst = *(bf16x8*)tmp;
  *(bf16x8*)(dst + 8) = *(bf16x8*)(tmp + 8);
}

// ---------------------------------------------------------------------------
// 2b) LDS-tiled transpose: Vd[b,h,s,dv] bf16 -> Vt[b,h,dv,s] bf16
//     grid (16 s-tiles, 64 bh), block 256
// ---------------------------------------------------------------------------
__global__ __launch_bounds__(256) void vtrans(const bf16* __restrict__ Vd,
                                              bf16* __restrict__ Vt) {
  __shared__ bf16 tile[64][72];
  int st = blockIdx.x, bh = blockIdx.y;
  const bf16* src = Vd + ((long)bh * 1024 + st * 64) * 64;
  int t = threadIdx.x;
#pragma unroll
  for (int i = 0; i < 2; ++i) {
    int chunk = t + i * 256;           // 512 chunks of 8 bf16
    int r = chunk >> 3, c8 = chunk & 7;
    *(bf16x8*)&tile[r][c8 * 8] = *(const bf16x8*)(src + r * 64 + c8 * 8);
  }
  __syncthreads();
  int d = t & 63, sc = t >> 6;
  bf16 tmp[16];
#pragma unroll
  for (int j = 0; j < 16; ++j) tmp[j] = tile[sc * 16 + j][d];
  bf16* dst = Vt + ((long)bh * 64 + d) * 1024 + st * 64 + sc * 16;
  *(bf16x8*)dst = *(bf16x8*)tmp;
  *(bf16x8*)(dst + 8) = *(bf16x8*)(tmp + 8);
}

// ---------------------------------------------------------------------------
// shared GEMM mainloop: C[128x128] += A[128xK] * BT[128xK]^T, K = 1024
// ---------------------------------------------------------------------------
__device__ __forceinline__ void gemm_mainloop(
    const bf16* __restrict__ A, const bf16* __restrict__ BT, bf16* As,
    bf16* Bs, int m0, int n0, f32x4 acc[4][4]) {
  const int tid = threadIdx.x;
  const int lane = tid & 63, wave = tid >> 6;
  const int wm = wave >> 1, wn = wave & 1;
  const int ln = lane & 15, ko8 = (lane >> 4) * 8;
  const int c0 = tid, c1 = 256 + tid;
  const int r0 = c0 >> 2, q0 = c0 & 3;
  const int r1 = c1 >> 2, q1 = c1 & 3;

  for (int k0 = 0; k0 < 1024; k0 += 32) {
    GLOBAL_TO_LDS16(A + (long)(m0 + r0) * 1024 + k0 + q0 * 8, As + c0 * 8);
    GLOBAL_TO_LDS16(A + (long)(m0 + r1) * 1024 + k0 + q1 * 8, As + c1 * 8);
    GLOBAL_TO_LDS16(BT + (long)(n0 + r0) * 1024 + k0 + q0 * 8, Bs + c0 * 8);
    GLOBAL_TO_LDS16(BT + (long)(n0 + r1) * 1024 + k0 + q1 * 8, Bs + c1 * 8);
    __syncthreads();
    bf16x8 af[4], bg[4];
#pragma unroll
    for (int t = 0; t < 4; ++t) {
      af[t] = *(const bf16x8*)(As + (wm * 64 + t * 16 + ln) * 32 + ko8);
      bg[t] = *(const bf16x8*)(Bs + (wn * 64 + t * 16 + ln) * 32 + ko8);
    }
#pragma unroll
    for (int i = 0; i < 4; ++i)
#pragma unroll
      for (int j = 0; j < 4; ++j) acc[i][j] = MFMA16(af[i], bg[j], acc[i][j]);
    __syncthreads();
  }
}

// ---------------------------------------------------------------------------
// 3) QKV projections -> [b,h,s,dk] for all three (coalesced epilogue).
//    z=0: Q (alpha = 1/32)  z=1: K  z=2: V (transposed later by vtrans)
// ---------------------------------------------------------------------------
__global__ __launch_bounds__(256) void qkv_gemm(
    const bf16* __restrict__ qb, const bf16* __restrict__ kb,
    const bf16* __restrict__ vb, const bf16* __restrict__ wqT,
    const bf16* __restrict__ wkT, const bf16* __restrict__ wvT,
    bf16* __restrict__ Qd, bf16* __restrict__ Kd, bf16* __restrict__ Vd) {
  __shared__ bf16 As[128 * 32];
  __shared__ bf16 Bs[128 * 32];
  int z = blockIdx.z;
  const bf16* A = (z == 0) ? qb : ((z == 1) ? kb : vb);
  const bf16* BT = (z == 0) ? wqT : ((z == 1) ? wkT : wvT);
  int m0 = blockIdx.x * 128, n0 = blockIdx.y * 128;
  f32x4 acc[4][4] = {};
  gemm_mainloop(A, BT, As, Bs, m0, n0, acc);

  const int tid = threadIdx.x, lane = tid & 63, wave = tid >> 6;
  const int wm = wave >> 1, wn = wave & 1, ln = lane & 15, lk = lane >> 4;
  const float alpha = (z == 0) ? 0.03125f : 1.0f;
  bf16* dst = (z == 0) ? Qd : ((z == 1) ? Kd : Vd);
#pragma unroll
  for (int ti = 0; ti < 4; ++ti)
#pragma unroll
    for (int tj = 0; tj < 4; ++tj) {
      int n = n0 + wn * 64 + tj * 16 + ln;
#pragma unroll
      for (int i = 0; i < 4; ++i) {
        int m = m0 + wm * 64 + ti * 16 + lk * 4 + i;
        // [b,h,s,dk]: ((b*16+h)*1024 + s)*64 + dk
        long addr =
            ((((long)(m >> 10) * 16 + (n >> 6)) << 10) + (m & 1023)) * 64 +
            (n & 63);
        dst[addr] = (bf16)(acc[ti][tj][i] * alpha);
      }
    }
}

// ---------------------------------------------------------------------------
// 4) fused attention: swapped-operand QK^T (scores^T in regs: col = q) ->
//    exact softmax (2-shfl reduce) -> vectorized attns f32x4 store + P bf16x4
//    LDS store -> PV
// ---------------------------------------------------------------------------
__global__ __launch_bounds__(256, 2) void attn_kernel(
    const bf16* __restrict__ Qd, const bf16* __restrict__ Kd,
    const bf16* __restrict__ Vtd, float* __restrict__ attns,
    bf16* __restrict__ Ob) {
  __shared__ bf16 P[16 * 1024];
  __shared__ float wstats[4][16][2];

  int qt = blockIdx.x, h = blockIdx.y, b = blockIdx.z;
  int q0 = qt * 16;
  int tid = threadIdx.x, lane = tid & 63, wave = tid >> 6;
  int ln = lane & 15, lk = lane >> 4;

  const bf16* Qbh = Qd + (((long)(b * 16 + h)) << 10) * 64;
  const bf16* Kbh = Kd + (((long)(b * 16 + h)) << 10) * 64;
  const bf16* Vbh = Vtd + (((long)(b * 16 + h)) << 6) * 1024;

  // B-operand (output cols = q): Q[q0+ln][lk*8 ..]
  bf16x8 bq0 = *(const bf16x8*)(Qbh + (long)(q0 + ln) * 64 + lk * 8);
  bf16x8 bq1 = *(const bf16x8*)(Qbh + (long)(q0 + ln) * 64 + 32 + lk * 8);

  // scores^T: sacc[t][i] = S[key = wave*256 + t*16 + lk*4 + i][q = q0 + ln]
  f32x4 sacc[16];
#pragma unroll
  for (int t = 0; t < 16; ++t) {
    int sk0 = wave * 256 + t * 16;
    f32x4 a = {0.f, 0.f, 0.f, 0.f};
    bf16x8 ak0 = *(const bf16x8*)(Kbh + (long)(sk0 + ln) * 64 + lk * 8);
    bf16x8 ak1 = *(const bf16x8*)(Kbh + (long)(sk0 + ln) * 64 + 32 + lk * 8);
    a = MFMA16(ak0, bq0, a);
    a = MFMA16(ak1, bq1, a);
    sacc[t] = a;
  }

  // per-q (=ln) stats over this wave's 256 keys: in-thread 64, then 2 shfls
  float m = sacc[0][0];
#pragma unroll
  for (int t = 0; t < 16; ++t)
#pragma unroll
    for (int i = 0; i < 4; ++i) m = fmaxf(m, sacc[t][i]);
  m = fmaxf(m, __shfl_xor(m, 16, 64));
  m = fmaxf(m, __shfl_xor(m, 32, 64));
  float s = 0.f;
#pragma unroll
  for (int t = 0; t < 16; ++t)
#pragma unroll
    for (int i = 0; i < 4; ++i) {
      float e = __expf(sacc[t][i] - m);
      sacc[t][i] = e;
      s += e;
    }
  s += __shfl_xor(s, 16, 64);
  s += __shfl_xor(s, 32, 64);
  if (lk == 0) {
    wstats[wave][ln][0] = m;
    wstats[wave][ln][1] = s;
  }
  __syncthreads();

  float M = fmaxf(fmaxf(wstats[0][ln][0], wstats[1][ln][0]),
                  fmaxf(wstats[2][ln][0], wstats[3][ln][0]));
  float L = 0.f;
#pragma unroll
  for (int w = 0; w < 4; ++w)
    L += wstats[w][ln][1] * __expf(wstats[w][ln][0] - M);
  float fscale = __expf(m - M) / L;

  // vectorized epilogue: 16x f32x4 global + 16x bf16x4 LDS per thread
  float* arow = attns + ((((long)(h * 4 + b)) << 10) + q0 + ln) * 1024 +
                wave * 256 + lk * 4;
#pragma unroll
  for (int t = 0; t < 16; ++t) {
    f32x4 av;
    bf16x4 pv;
#pragma unroll
    for (int i = 0; i < 4; ++i) {
      av[i] = sacc[t][i] * fscale;
      pv[i] = (bf16)av[i];
    }
    *(f32x4*)(arow + t * 16) = av;
    int col = wave * 256 + t * 16 + lk * 4;
    int g = col >> 3;
    *(bf16x4*)(P + (ln << 10) + ((g ^ (ln & 7)) << 3) + (col & 7)) = pv;
  }
  __syncthreads();

  f32x4 oacc = {0.f, 0.f, 0.f, 0.f};
#pragma unroll 4
  for (int s0 = 0; s0 < 1024; s0 += 32) {
    int g = (s0 >> 3) + lk;
    bf16x8 ap = *(const bf16x8*)(P + (ln << 10) + ((g ^ (ln & 7)) << 3));
    bf16x8 bv =
        *(const bf16x8*)(Vbh + (long)(wave * 16 + ln) * 1024 + s0 + lk * 8);
    oacc = MFMA16(ap, bv, oacc);
  }
#pragma unroll
  for (int i = 0; i < 4; ++i) {
    int qrow = q0 + lk * 4 + i;
    Ob[((((long)b) << 10) + qrow) * 1024 + (h << 6) + wave * 16 + ln] =
        (bf16)oacc[i];
  }
}

// ---------------------------------------------------------------------------
// 5) out = O @ w_proj^T + b_proj  (fp32 out)
// ---------------------------------------------------------------------------
__global__ __launch_bounds__(256) void out_gemm(
    const bf16* __restrict__ Ob, const bf16* __restrict__ wpb,
    const float* __restrict__ bias, float* __restrict__ out) {
  __shared__ bf16 As[128 * 32];
  __shared__ bf16 Bs[128 * 32];
  int m0 = blockIdx.x * 128, n0 = blockIdx.y * 128;
  f32x4 acc[4][4] = {};
  gemm_mainloop(Ob, wpb, As, Bs, m0, n0, acc);

  const int tid = threadIdx.x, lane = tid & 63, wave = tid >> 6;
  const int wm = wave >> 1, wn = wave & 1, ln = lane & 15, lk = lane >> 4;
#pragma unroll
  for (int ti = 0; ti < 4; ++ti)
#pragma unroll
    for (int tj = 0; tj < 4; ++tj) {
      int n = n0 + wn * 64 + tj * 16 + ln;
      float bn = bias[n];
#pragma unroll
      for (int i = 0; i < 4; ++i) {
        int m = m0 + wm * 64 + ti * 16 + lk * 4 + i;
        out[(long)m * 1024 + n] = acc[ti][tj][i] + bn;
      }
    }
}

// ---------------------------------------------------------------------------
extern "C" void kernel_launch(void* const* d_in, const int* in_sizes, int n_in,
                              void* d_out, int out_size, void* d_ws,
                              size_t ws_size, hipStream_t stream) {
  const float* query = (const float*)d_in[0];
  const float* key = (const float*)d_in[1];
  const float* value = (const float*)d_in[2];
  const float* w_q = (const float*)d_in[3];
  const float* w_k = (const float*)d_in[4];
  const float* w_v = (const float*)d_in[5];
  const float* w_proj = (const float*)d_in[6];
  const float* b_proj = (const float*)d_in[7];

  char* ws = (char*)d_ws;
  bf16* qb = (bf16*)(ws);                  // 8 MB  [4096,1024]
  bf16* kb = (bf16*)(ws + (8ul << 20));    // 8 MB
  bf16* vb = (bf16*)(ws + (16ul << 20));   // 8 MB
  bf16* wqT = (bf16*)(ws + (24ul << 20));  // 2 MB  [1024,1024] BT
  bf16* wkT = (bf16*)(ws + (26ul << 20));  // 2 MB
  bf16* wvT = (bf16*)(ws + (28ul << 20));  // 2 MB
  bf16* wpb = (bf16*)(ws + (30ul << 20));  // 2 MB  w_proj BT layout
  bf16* Qd = (bf16*)(ws + (32ul << 20));   // 8 MB  [b,h,s,dk]
  bf16* Kd = (bf16*)(ws + (40ul << 20));   // 8 MB  [b,h,s,dk]
  bf16* Vtd = (bf16*)(ws + (48ul << 20));  // 8 MB  [b,h,dv,s]
  bf16* Ob = (bf16*)(ws + (56ul << 20));   // 8 MB  [b*sq, h*dv]
  bf16* Vd = (bf16*)(ws + (64ul << 20));   // 8 MB  [b,h,s,dv]
  // total 72 MB of d_ws

  float* out = (float*)d_out;              // [4096, 1024] fp32
  float* attns = out + 4194304;            // [64, 1024, 1024] fp32

  cvt_all<<<13312, 256, 0, stream>>>(query, key, value, w_proj, qb, kb, vb,
                                     wpb);
  wtrans<<<dim3(16, 16, 3), 256, 0, stream>>>(w_q, w_k, w_v, wqT, wkT, wvT);
  qkv_gemm<<<dim3(32, 8, 3), 256, 0, stream>>>(qb, kb, vb, wqT, wkT, wvT, Qd,
                                               Kd, Vd);
  vtrans<<<dim3(16, 64), 256, 0, stream>>>(Vd, Vtd);
  attn_kernel<<<dim3(64, 16, 4), 256, 0, stream>>>(Qd, Kd, Vtd, attns, Ob);
  out_gemm<<<dim3(32, 8), 256, 0, stream>>>(Ob, wpb, b_proj, out);
}

// Round 3
// 512.976 us; speedup vs baseline: 1.0084x; 1.0084x over previous
//
#include <hip/hip_runtime.h>
#include <cstdint>

typedef __bf16 bf16;
typedef bf16 bf16x8 __attribute__((ext_vector_type(8)));
typedef bf16 bf16x4 __attribute__((ext_vector_type(4)));
typedef float f32x4 __attribute__((ext_vector_type(4)));

#define MFMA16(a, b, c) __builtin_amdgcn_mfma_f32_16x16x32_bf16((a), (b), (c), 0, 0, 0)

#define GLOBAL_TO_LDS16(gptr, lptr)                                          \
  __builtin_amdgcn_global_load_lds(                                          \
      (const __attribute__((address_space(1))) void*)(gptr),                 \
      (__attribute__((address_space(3))) void*)(lptr), 16, 0, 0)

// problem dims: H=16, D=1024, DK=DV=64, B=4, SQ=SK=1024, scale = 32

// ---------------------------------------------------------------------------
// 1) flat fp32 -> bf16 convert for query/key/value/w_proj
// ---------------------------------------------------------------------------
__global__ __launch_bounds__(256) void cvt_all(
    const float* __restrict__ q, const float* __restrict__ k,
    const float* __restrict__ v, const float* __restrict__ wp,
    bf16* __restrict__ qb, bf16* __restrict__ kb,
    bf16* __restrict__ vb, bf16* __restrict__ wpb) {
  long i4 = ((long)blockIdx.x * 256 + threadIdx.x) * 4;
  const float* src;
  bf16* dst;
  long off;
  if (i4 < 4194304) {
    src = q; dst = qb; off = i4;
  } else if (i4 < 8388608) {
    src = k; dst = kb; off = i4 - 4194304;
  } else if (i4 < 12582912) {
    src = v; dst = vb; off = i4 - 8388608;
  } else {
    src = wp; dst = wpb; off = i4 - 12582912;
  }
  float4 f = *(const float4*)(src + off);
  bf16x4 o;
  o[0] = (bf16)f.x; o[1] = (bf16)f.y; o[2] = (bf16)f.z; o[3] = (bf16)f.w;
  *(bf16x4*)(dst + off) = o;
}

// ---------------------------------------------------------------------------
// 2) LDS-tiled transpose: w_{q,k,v}[h][d][kk] fp32 -> wT[h*64+kk][d] bf16
//    grid (16 d-tiles, 16 h, 3 matrices), block 256
// ---------------------------------------------------------------------------
__global__ __launch_bounds__(256) void wtrans(
    const float* __restrict__ wq, const float* __restrict__ wk,
    const float* __restrict__ wv, bf16* __restrict__ wqT,
    bf16* __restrict__ wkT, bf16* __restrict__ wvT) {
  __shared__ bf16 tile[64][72];  // 72: 144 B row stride, conflict-free gather
  int dt = blockIdx.x, h = blockIdx.y, z = blockIdx.z;
  const float* src =
      ((z == 0) ? wq : (z == 1) ? wk : wv) + (long)h * 65536 + dt * 64 * 64;
  bf16* dstM = (z == 0) ? wqT : (z == 1) ? wkT : wvT;
  int t = threadIdx.x;
#pragma unroll
  for (int i = 0; i < 4; ++i) {
    int chunk = t + i * 256;           // 1024 chunks of 4 floats
    int r = chunk >> 4, c4 = chunk & 15;
    float4 f = *(const float4*)(src + r * 64 + c4 * 4);
    bf16x4 o;
    o[0] = (bf16)f.x; o[1] = (bf16)f.y; o[2] = (bf16)f.z; o[3] = (bf16)f.w;
    *(bf16x4*)&tile[r][c4 * 4] = o;
  }
  __syncthreads();
  int kk = t & 63, sc = t >> 6;        // gather 16 d's for this kk
  bf16 tmp[16];
#pragma unroll
  for (int j = 0; j < 16; ++j) tmp[j] = tile[sc * 16 + j][kk];
  bf16* dst = dstM + ((long)h * 64 + kk) * 1024 + dt * 64 + sc * 16;
  *(bf16x8*)dst = *(bf16x8*)tmp;
  *(bf16x8*)(dst + 8) = *(bf16x8*)(tmp + 8);
}

// ---------------------------------------------------------------------------
// 2b) LDS-tiled transpose: Vd[b,h,s,dv] bf16 -> Vt[b,h,dv,s] bf16
//     grid (16 s-tiles, 64 bh), block 256
// ---------------------------------------------------------------------------
__global__ __launch_bounds__(256) void vtrans(const bf16* __restrict__ Vd,
                                              bf16* __restrict__ Vt) {
  __shared__ bf16 tile[64][72];
  int st = blockIdx.x, bh = blockIdx.y;
  const bf16* src = Vd + ((long)bh * 1024 + st * 64) * 64;
  int t = threadIdx.x;
#pragma unroll
  for (int i = 0; i < 2; ++i) {
    int chunk = t + i * 256;           // 512 chunks of 8 bf16
    int r = chunk >> 3, c8 = chunk & 7;
    *(bf16x8*)&tile[r][c8 * 8] = *(const bf16x8*)(src + r * 64 + c8 * 8);
  }
  __syncthreads();
  int d = t & 63, sc = t >> 6;
  bf16 tmp[16];
#pragma unroll
  for (int j = 0; j < 16; ++j) tmp[j] = tile[sc * 16 + j][d];
  bf16* dst = Vt + ((long)bh * 64 + d) * 1024 + st * 64 + sc * 16;
  *(bf16x8*)dst = *(bf16x8*)tmp;
  *(bf16x8*)(dst + 8) = *(bf16x8*)(tmp + 8);
}

// ---------------------------------------------------------------------------
// shared GEMM mainloop: C[128x128] += A[128xK] * BT[128xK]^T, K = 1024
// ---------------------------------------------------------------------------
__device__ __forceinline__ void gemm_mainloop(
    const bf16* __restrict__ A, const bf16* __restrict__ BT, bf16* As,
    bf16* Bs, int m0, int n0, f32x4 acc[4][4]) {
  const int tid = threadIdx.x;
  const int lane = tid & 63, wave = tid >> 6;
  const int wm = wave >> 1, wn = wave & 1;
  const int ln = lane & 15, ko8 = (lane >> 4) * 8;
  const int c0 = tid, c1 = 256 + tid;
  const int r0 = c0 >> 2, q0 = c0 & 3;
  const int r1 = c1 >> 2, q1 = c1 & 3;

  for (int k0 = 0; k0 < 1024; k0 += 32) {
    GLOBAL_TO_LDS16(A + (long)(m0 + r0) * 1024 + k0 + q0 * 8, As + c0 * 8);
    GLOBAL_TO_LDS16(A + (long)(m0 + r1) * 1024 + k0 + q1 * 8, As + c1 * 8);
    GLOBAL_TO_LDS16(BT + (long)(n0 + r0) * 1024 + k0 + q0 * 8, Bs + c0 * 8);
    GLOBAL_TO_LDS16(BT + (long)(n0 + r1) * 1024 + k0 + q1 * 8, Bs + c1 * 8);
    __syncthreads();
    bf16x8 af[4], bg[4];
#pragma unroll
    for (int t = 0; t < 4; ++t) {
      af[t] = *(const bf16x8*)(As + (wm * 64 + t * 16 + ln) * 32 + ko8);
      bg[t] = *(const bf16x8*)(Bs + (wn * 64 + t * 16 + ln) * 32 + ko8);
    }
#pragma unroll
    for (int i = 0; i < 4; ++i)
#pragma unroll
      for (int j = 0; j < 4; ++j) acc[i][j] = MFMA16(af[i], bg[j], acc[i][j]);
    __syncthreads();
  }
}

// ---------------------------------------------------------------------------
// 3) QKV projections -> [b,h,s,dk] for all three (coalesced epilogue).
//    z=0: Q (alpha = 1/32)  z=1: K  z=2: V (transposed later by vtrans)
// ---------------------------------------------------------------------------
__global__ __launch_bounds__(256) void qkv_gemm(
    const bf16* __restrict__ qb, const bf16* __restrict__ kb,
    const bf16* __restrict__ vb, const bf16* __restrict__ wqT,
    const bf16* __restrict__ wkT, const bf16* __restrict__ wvT,
    bf16* __restrict__ Qd, bf16* __restrict__ Kd, bf16* __restrict__ Vd) {
  __shared__ bf16 As[128 * 32];
  __shared__ bf16 Bs[128 * 32];
  int z = blockIdx.z;
  const bf16* A = (z == 0) ? qb : ((z == 1) ? kb : vb);
  const bf16* BT = (z == 0) ? wqT : ((z == 1) ? wkT : wvT);
  int m0 = blockIdx.x * 128, n0 = blockIdx.y * 128;
  f32x4 acc[4][4] = {};
  gemm_mainloop(A, BT, As, Bs, m0, n0, acc);

  const int tid = threadIdx.x, lane = tid & 63, wave = tid >> 6;
  const int wm = wave >> 1, wn = wave & 1, ln = lane & 15, lk = lane >> 4;
  const float alpha = (z == 0) ? 0.03125f : 1.0f;
  bf16* dst = (z == 0) ? Qd : ((z == 1) ? Kd : Vd);
#pragma unroll
  for (int ti = 0; ti < 4; ++ti)
#pragma unroll
    for (int tj = 0; tj < 4; ++tj) {
      int n = n0 + wn * 64 + tj * 16 + ln;
#pragma unroll
      for (int i = 0; i < 4; ++i) {
        int m = m0 + wm * 64 + ti * 16 + lk * 4 + i;
        // [b,h,s,dk]: ((b*16+h)*1024 + s)*64 + dk
        long addr =
            ((((long)(m >> 10) * 16 + (n >> 6)) << 10) + (m & 1023)) * 64 +
            (n & 63);
        dst[addr] = (bf16)(acc[ti][tj][i] * alpha);
      }
    }
}

// ---------------------------------------------------------------------------
// 4) fused attention: swapped-operand QK^T (scores^T in regs: col = q) ->
//    exact softmax (2-shfl reduce) -> vectorized attns f32x4 store + P bf16x4
//    LDS store -> PV
//    Occupancy experiment: 4 blocks/CU (was 2). LDS = 32.5 KB/block fits 4;
//    VGPR peak ~120 fits the 128 cap from min-4-waves/EU.
// ---------------------------------------------------------------------------
__global__ __launch_bounds__(256, 4) void attn_kernel(
    const bf16* __restrict__ Qd, const bf16* __restrict__ Kd,
    const bf16* __restrict__ Vtd, float* __restrict__ attns,
    bf16* __restrict__ Ob) {
  __shared__ bf16 P[16 * 1024];
  __shared__ float wstats[4][16][2];

  int qt = blockIdx.x, h = blockIdx.y, b = blockIdx.z;
  int q0 = qt * 16;
  int tid = threadIdx.x, lane = tid & 63, wave = tid >> 6;
  int ln = lane & 15, lk = lane >> 4;

  const bf16* Qbh = Qd + (((long)(b * 16 + h)) << 10) * 64;
  const bf16* Kbh = Kd + (((long)(b * 16 + h)) << 10) * 64;
  const bf16* Vbh = Vtd + (((long)(b * 16 + h)) << 6) * 1024;

  // B-operand (output cols = q): Q[q0+ln][lk*8 ..]
  bf16x8 bq0 = *(const bf16x8*)(Qbh + (long)(q0 + ln) * 64 + lk * 8);
  bf16x8 bq1 = *(const bf16x8*)(Qbh + (long)(q0 + ln) * 64 + 32 + lk * 8);

  // scores^T: sacc[t][i] = S[key = wave*256 + t*16 + lk*4 + i][q = q0 + ln]
  f32x4 sacc[16];
  __builtin_amdgcn_s_setprio(1);
#pragma unroll
  for (int t = 0; t < 16; ++t) {
    int sk0 = wave * 256 + t * 16;
    f32x4 a = {0.f, 0.f, 0.f, 0.f};
    bf16x8 ak0 = *(const bf16x8*)(Kbh + (long)(sk0 + ln) * 64 + lk * 8);
    bf16x8 ak1 = *(const bf16x8*)(Kbh + (long)(sk0 + ln) * 64 + 32 + lk * 8);
    a = MFMA16(ak0, bq0, a);
    a = MFMA16(ak1, bq1, a);
    sacc[t] = a;
  }
  __builtin_amdgcn_s_setprio(0);

  // per-q (=ln) stats over this wave's 256 keys: in-thread 64, then 2 shfls
  float m = sacc[0][0];
#pragma unroll
  for (int t = 0; t < 16; ++t)
#pragma unroll
    for (int i = 0; i < 4; ++i) m = fmaxf(m, sacc[t][i]);
  m = fmaxf(m, __shfl_xor(m, 16, 64));
  m = fmaxf(m, __shfl_xor(m, 32, 64));
  float s = 0.f;
#pragma unroll
  for (int t = 0; t < 16; ++t)
#pragma unroll
    for (int i = 0; i < 4; ++i) {
      float e = __expf(sacc[t][i] - m);
      sacc[t][i] = e;
      s += e;
    }
  s += __shfl_xor(s, 16, 64);
  s += __shfl_xor(s, 32, 64);
  if (lk == 0) {
    wstats[wave][ln][0] = m;
    wstats[wave][ln][1] = s;
  }
  __syncthreads();

  float M = fmaxf(fmaxf(wstats[0][ln][0], wstats[1][ln][0]),
                  fmaxf(wstats[2][ln][0], wstats[3][ln][0]));
  float L = 0.f;
#pragma unroll
  for (int w = 0; w < 4; ++w)
    L += wstats[w][ln][1] * __expf(wstats[w][ln][0] - M);
  float fscale = __expf(m - M) / L;

  // vectorized epilogue: 16x f32x4 global + 16x bf16x4 LDS per thread
  float* arow = attns + ((((long)(h * 4 + b)) << 10) + q0 + ln) * 1024 +
                wave * 256 + lk * 4;
#pragma unroll
  for (int t = 0; t < 16; ++t) {
    f32x4 av;
    bf16x4 pv;
#pragma unroll
    for (int i = 0; i < 4; ++i) {
      av[i] = sacc[t][i] * fscale;
      pv[i] = (bf16)av[i];
    }
    *(f32x4*)(arow + t * 16) = av;
    int col = wave * 256 + t * 16 + lk * 4;
    int g = col >> 3;
    *(bf16x4*)(P + (ln << 10) + ((g ^ (ln & 7)) << 3) + (col & 7)) = pv;
  }
  __syncthreads();

  f32x4 oacc = {0.f, 0.f, 0.f, 0.f};
  __builtin_amdgcn_s_setprio(1);
#pragma unroll 4
  for (int s0 = 0; s0 < 1024; s0 += 32) {
    int g = (s0 >> 3) + lk;
    bf16x8 ap = *(const bf16x8*)(P + (ln << 10) + ((g ^ (ln & 7)) << 3));
    bf16x8 bv =
        *(const bf16x8*)(Vbh + (long)(wave * 16 + ln) * 1024 + s0 + lk * 8);
    oacc = MFMA16(ap, bv, oacc);
  }
  __builtin_amdgcn_s_setprio(0);
#pragma unroll
  for (int i = 0; i < 4; ++i) {
    int qrow = q0 + lk * 4 + i;
    Ob[((((long)b) << 10) + qrow) * 1024 + (h << 6) + wave * 16 + ln] =
        (bf16)oacc[i];
  }
}

// ---------------------------------------------------------------------------
// 5) out = O @ w_proj^T + b_proj  (fp32 out)
// ---------------------------------------------------------------------------
__global__ __launch_bounds__(256) void out_gemm(
    const bf16* __restrict__ Ob, const bf16* __restrict__ wpb,
    const float* __restrict__ bias, float* __restrict__ out) {
  __shared__ bf16 As[128 * 32];
  __shared__ bf16 Bs[128 * 32];
  int m0 = blockIdx.x * 128, n0 = blockIdx.y * 128;
  f32x4 acc[4][4] = {};
  gemm_mainloop(Ob, wpb, As, Bs, m0, n0, acc);

  const int tid = threadIdx.x, lane = tid & 63, wave = tid >> 6;
  const int wm = wave >> 1, wn = wave & 1, ln = lane & 15, lk = lane >> 4;
#pragma unroll
  for (int ti = 0; ti < 4; ++ti)
#pragma unroll
    for (int tj = 0; tj < 4; ++tj) {
      int n = n0 + wn * 64 + tj * 16 + ln;
      float bn = bias[n];
#pragma unroll
      for (int i = 0; i < 4; ++i) {
        int m = m0 + wm * 64 + ti * 16 + lk * 4 + i;
        out[(long)m * 1024 + n] = acc[ti][tj][i] + bn;
      }
    }
}

// ---------------------------------------------------------------------------
extern "C" void kernel_launch(void* const* d_in, const int* in_sizes, int n_in,
                              void* d_out, int out_size, void* d_ws,
                              size_t ws_size, hipStream_t stream) {
  const float* query = (const float*)d_in[0];
  const float* key = (const float*)d_in[1];
  const float* value = (const float*)d_in[2];
  const float* w_q = (const float*)d_in[3];
  const float* w_k = (const float*)d_in[4];
  const float* w_v = (const float*)d_in[5];
  const float* w_proj = (const float*)d_in[6];
  const float* b_proj = (const float*)d_in[7];

  char* ws = (char*)d_ws;
  bf16* qb = (bf16*)(ws);                  // 8 MB  [4096,1024]
  bf16* kb = (bf16*)(ws + (8ul << 20));    // 8 MB
  bf16* vb = (bf16*)(ws + (16ul << 20));   // 8 MB
  bf16* wqT = (bf16*)(ws + (24ul << 20));  // 2 MB  [1024,1024] BT
  bf16* wkT = (bf16*)(ws + (26ul << 20));  // 2 MB
  bf16* wvT = (bf16*)(ws + (28ul << 20));  // 2 MB
  bf16* wpb = (bf16*)(ws + (30ul << 20));  // 2 MB  w_proj BT layout
  bf16* Qd = (bf16*)(ws + (32ul << 20));   // 8 MB  [b,h,s,dk]
  bf16* Kd = (bf16*)(ws + (40ul << 20));   // 8 MB  [b,h,s,dk]
  bf16* Vtd = (bf16*)(ws + (48ul << 20));  // 8 MB  [b,h,dv,s]
  bf16* Ob = (bf16*)(ws + (56ul << 20));   // 8 MB  [b*sq, h*dv]
  bf16* Vd = (bf16*)(ws + (64ul << 20));   // 8 MB  [b,h,s,dv]
  // total 72 MB of d_ws

  float* out = (float*)d_out;              // [4096, 1024] fp32
  float* attns = out + 4194304;            // [64, 1024, 1024] fp32

  cvt_all<<<13312, 256, 0, stream>>>(query, key, value, w_proj, qb, kb, vb,
                                     wpb);
  wtrans<<<dim3(16, 16, 3), 256, 0, stream>>>(w_q, w_k, w_v, wqT, wkT, wvT);
  qkv_gemm<<<dim3(32, 8, 3), 256, 0, stream>>>(qb, kb, vb, wqT, wkT, wvT, Qd,
                                               Kd, Vd);
  vtrans<<<dim3(16, 64), 256, 0, stream>>>(Vd, Vtd);
  attn_kernel<<<dim3(64, 16, 4), 256, 0, stream>>>(Qd, Kd, Vtd, attns, Ob);
  out_gemm<<<dim3(32, 8), 256, 0, stream>>>(Ob, wpb, b_proj, out);
}